// Round 9
// baseline (100.625 us; speedup 1.0000x reference)
//
#include <hip/hip_runtime.h>
#include <hip/hip_bf16.h>

#define NROWS 8192
#define NDIM  256
#define KNN   8
#define TCOL  32                          // j-cols per LDS tile (16 KiB)
#define BLK_ROWS 256                      // 4 waves x 64 rows (R=2)

typedef __attribute__((ext_vector_type(8)))  short bf16x8;
typedef __attribute__((ext_vector_type(16))) float f32x16;

// ---- workspace layout (bytes) ----
#define WS_EBF 0                          // 8192*256*2 = 4 MiB (row-major bf16)
#define WS_SQN (4*1024*1024)              // 32 KiB
#define WS_PCS (WS_SQN + 32*1024)         // 128 x 256 f32 = 128 KiB
#define WS_ACC (WS_PCS + 128*1024)        // gacc[0..2] + counter
#define WS_KNN (WS_ACC + 1024)            // [jsplit][NROWS][KNN] f32

// e -> bf16 row-major, per-row squared norms, per-block colsum partials.
// Block 0 zeroes gacc+counter (only k_final reads them; stream-ordered).
__global__ void k_prep(const float* __restrict__ e,
                       ushort* __restrict__ ebf,
                       float* __restrict__ sqn,
                       float* __restrict__ pcs,
                       float* __restrict__ gacc) {
  __shared__ float lcs[NDIM];
  const int tid  = threadIdx.x;
  const int lane = tid & 63;
  const int wv   = tid >> 6;
  if (blockIdx.x == 0 && tid < 8) ((int*)gacc)[tid] = 0;
  lcs[tid] = 0.f;
  __syncthreads();
  float4 cs = {0.f, 0.f, 0.f, 0.f};
  #pragma unroll
  for (int r = 0; r < 16; ++r) {
    const int row = blockIdx.x * 64 + wv * 16 + r;
    const float4 v = *reinterpret_cast<const float4*>(e + (size_t)row * NDIM + lane * 4);
    ushort4 o;
    __hip_bfloat16 b0 = __float2bfloat16(v.x), b1 = __float2bfloat16(v.y);
    __hip_bfloat16 b2 = __float2bfloat16(v.z), b3 = __float2bfloat16(v.w);
    o.x = *reinterpret_cast<ushort*>(&b0); o.y = *reinterpret_cast<ushort*>(&b1);
    o.z = *reinterpret_cast<ushort*>(&b2); o.w = *reinterpret_cast<ushort*>(&b3);
    *reinterpret_cast<ushort4*>(ebf + (size_t)row * NDIM + lane * 4) = o;
    float acc = v.x*v.x + v.y*v.y + v.z*v.z + v.w*v.w;
    #pragma unroll
    for (int off = 32; off > 0; off >>= 1) acc += __shfl_down(acc, off);
    if (lane == 0) sqn[row] = acc;
    cs.x += v.x; cs.y += v.y; cs.z += v.z; cs.w += v.w;
  }
  atomicAdd(&lcs[lane * 4 + 0], cs.x);
  atomicAdd(&lcs[lane * 4 + 1], cs.y);
  atomicAdd(&lcs[lane * 4 + 2], cs.z);
  atomicAdd(&lcs[lane * 4 + 3], cs.w);
  __syncthreads();
  pcs[blockIdx.x * NDIM + tid] = lcs[tid];
}

// ---- selection helpers (MAX-key variants; key = dot - nj/2, larger=nearer) ----
__device__ __forceinline__ void CEmax(float& x, float& y) {
  const float hi = fmaxf(x, y);
  y = fminf(x, y);
  x = hi;
}
// sort a bitonic 8-sequence DESCENDING (3 substeps x 4 independent CEs)
__device__ __forceinline__ void clean8max(float* s) {
  CEmax(s[0],s[4]); CEmax(s[1],s[5]); CEmax(s[2],s[6]); CEmax(s[3],s[7]);
  CEmax(s[0],s[2]); CEmax(s[1],s[3]); CEmax(s[4],s[6]); CEmax(s[5],s[7]);
  CEmax(s[0],s[1]); CEmax(s[2],s[3]); CEmax(s[4],s[5]); CEmax(s[6],s[7]);
}
// descending sorted top-8 insert (med3 network, mirror of the min version)
__device__ __forceinline__ void ins8max(float* m, const float c) {
  m[7] = __builtin_amdgcn_fmed3f(m[6], m[7], c);
  m[6] = __builtin_amdgcn_fmed3f(m[5], m[6], c);
  m[5] = __builtin_amdgcn_fmed3f(m[4], m[5], c);
  m[4] = __builtin_amdgcn_fmed3f(m[3], m[4], c);
  m[3] = __builtin_amdgcn_fmed3f(m[2], m[3], c);
  m[2] = __builtin_amdgcn_fmed3f(m[1], m[2], c);
  m[1] = __builtin_amdgcn_fmed3f(m[0], m[1], c);
  m[0] = fmaxf(m[0], c);
}
// ascending clean (k_final merges ascending distance lists)
__device__ __forceinline__ void CEmin(float& x, float& y) {
  const float lo = fminf(x, y);
  y = fmaxf(x, y);
  x = lo;
}
__device__ __forceinline__ void clean8min(float* s) {
  CEmin(s[0],s[4]); CEmin(s[1],s[5]); CEmin(s[2],s[6]); CEmin(s[3],s[7]);
  CEmin(s[0],s[2]); CEmin(s[1],s[3]); CEmin(s[4],s[6]); CEmin(s[5],s[7]);
  CEmin(s[0],s[1]); CEmin(s[2],s[3]); CEmin(s[4],s[5]); CEmin(s[6],s[7]);
}

// Fused Gram + top-8, R=2, LDS-shared j-tiles, minimal per-iter VALU:
//  - stage source addresses hoisted (4 ptrs, += 16KB/iter)
//  - ds_read bases hoisted (8 XOR'd lane bases; kk/buf folded into imm offset
//    via unroll-by-2 so buffer parity is compile-time)
//  - acc init = -nj/2 -> MFMA output IS the selection key (no fmaf stage)
__launch_bounds__(256, 2)
__global__ void k_main(const ushort* __restrict__ eb,
                       const float* __restrict__ sqn,
                       float* __restrict__ knn_out,
                       int jrange, int jsplit) {
  __shared__ ushort lbuf[2][TCOL * NDIM];   // 2 x 16 KiB
  char* const lraw = reinterpret_cast<char*>(&lbuf[0][0]);

  const int tid  = threadIdx.x;
  const int lane = tid & 63;
  const int wv   = tid >> 6;
  const int col  = lane & 31;
  const int hi   = lane >> 5;
  const int rowA = blockIdx.x * BLK_ROWS + wv * 32 + col;
  const int rowB = rowA + 128;
  const int split = blockIdx.y;
  const int jbase = split * jrange;

  // i-fragments for both row-blocks (128 VGPRs, loop-invariant).
  bf16x8 ifA[16], ifB[16];
  #pragma unroll
  for (int kk = 0; kk < 16; ++kk) {
    ifA[kk] = *reinterpret_cast<const bf16x8*>(eb + (size_t)rowA * NDIM + kk * 16 + hi * 8);
    ifB[kk] = *reinterpret_cast<const bf16x8*>(eb + (size_t)rowB * NDIM + kk * 16 + hi * 8);
  }
  const float niA = sqn[rowA];
  const float niB = sqn[rowB];

  float mA[KNN], mB[KNN];
  #pragma unroll
  for (int i = 0; i < KNN; ++i) { mA[i] = -1e30f; mB[i] = -1e30f; }

  // hoisted per-lane stage source pointers (inverse-swizzled), advanced
  // by one tile (TCOL*NDIM elems) per staged tile.
  const ushort* sp[4];
  #pragma unroll
  for (int s = 0; s < 4; ++s) {
    const int o  = s * 4096 + wv * 1024 + lane * 16;
    const int kk = o >> 10;
    const int h  = (o >> 9) & 1;
    const int c  = ((o & 511) ^ ((kk & 7) << 4)) >> 4;
    sp[s] = eb + (size_t)(jbase + c) * NDIM + (kk * 2 + h) * 8;
  }
  // hoisted ds_read lane bases: addr = lbase[kk&7] + kk*1024 + buf*16384
  int lbase[8];
  #pragma unroll
  for (int w = 0; w < 8; ++w) lbase[w] = hi * 512 + ((col * 16) ^ (w << 4));

  auto STAGE = [&](int bufc) {
    #pragma unroll
    for (int s = 0; s < 4; ++s) {
      __builtin_amdgcn_global_load_lds(
          (const __attribute__((address_space(1))) void*)sp[s],
          (__attribute__((address_space(3))) void*)(
              lraw + bufc * 16384 + s * 4096 + wv * 1024),
          16, 0, 0);
      sp[s] += TCOL * NDIM;
    }
  };

  const float* njp = sqn + jbase;
  const int nT = jrange / TCOL;   // 8 or 16 (even)

  STAGE(0);
  asm volatile("s_waitcnt vmcnt(0)" ::: "memory");
  __syncthreads();

  auto BODY = [&](int bufc, int t) {
    if (t + 1 < nT) STAGE(bufc ^ 1);

    // acc init = -nj/2 for the j this reg owns: j_local = 8*(r>>2)+(r&3)+4*hi
    f32x16 accA, accB;
    #pragma unroll
    for (int g = 0; g < 4; ++g) {
      const float4 nj4 = *reinterpret_cast<const float4*>(njp + g * 8 + hi * 4);
      accA[g*4+0] = -0.5f * nj4.x; accA[g*4+1] = -0.5f * nj4.y;
      accA[g*4+2] = -0.5f * nj4.z; accA[g*4+3] = -0.5f * nj4.w;
    }
    accB = accA;

    __builtin_amdgcn_s_setprio(1);
    #pragma unroll
    for (int kk = 0; kk < 16; ++kk) {
      const bf16x8 jf = *reinterpret_cast<const bf16x8*>(
          lraw + bufc * 16384 + kk * 1024 + lbase[kk & 7]);
      accA = __builtin_amdgcn_mfma_f32_32x32x16_bf16(jf, ifA[kk], accA, 0, 0, 0);
      accB = __builtin_amdgcn_mfma_f32_32x32x16_bf16(jf, ifB[kk], accB, 0, 0, 0);
    }
    __builtin_amdgcn_s_setprio(0);

    // acc IS the key (larger = nearer); top-8 max selection
    #pragma unroll
    for (int q = 0; q < 16; ++q) ins8max(mA, accA[q]);
    #pragma unroll
    for (int q = 0; q < 16; ++q) ins8max(mB, accB[q]);

    njp += TCOL;
    asm volatile("s_waitcnt vmcnt(0)" ::: "memory");
    __syncthreads();
  };

  for (int t = 0; t < nT; t += 2) {
    BODY(0, t);
    BODY(1, t + 1);
  }

  // merge k-half lists (lane <-> lane+32): top-8 largest of two descending
  // sorted lists = elementwise max(a_k, b_{7-k}) (bitonic), then clean.
  // dist = ni - 2*key -> descending key == ascending distance.
  float g[KNN];
  #pragma unroll
  for (int k = 0; k < KNN; ++k)
    g[k] = fmaxf(mA[k], __shfl_xor(mA[KNN - 1 - k], 32));
  clean8max(g);
  if (hi == 0) {
    float* dst = knn_out + ((size_t)split * NROWS + rowA) * KNN;
    #pragma unroll
    for (int k = 0; k < KNN; ++k)
      dst[k] = fmaxf(fmaf(-2.0f, g[k], niA), 0.0f);
  }
  #pragma unroll
  for (int k = 0; k < KNN; ++k)
    g[k] = fmaxf(mB[k], __shfl_xor(mB[KNN - 1 - k], 32));
  clean8max(g);
  if (hi == 0) {
    float* dst = knn_out + ((size_t)split * NROWS + rowB) * KNN;
    #pragma unroll
    for (int k = 0; k < KNN; ++k)
      dst[k] = fmaxf(fmaf(-2.0f, g[k], niB), 0.0f);
  }
}

// Merge jsplit ascending sorted 8-lists per row; reduce sum8/S2; block 0
// reduces colsum partials -> Q; last finishing block computes the scalar.
__global__ void k_final(const float* __restrict__ knn,
                        const float* __restrict__ sqn,
                        const float* __restrict__ pcs,
                        float* __restrict__ gacc,
                        float* __restrict__ out, int jsplit) {
  const int tid = threadIdx.x;
  const int row = blockIdx.x * blockDim.x + tid;
  float m[KNN];
  const float* p0 = knn + (size_t)row * KNN;
  #pragma unroll
  for (int i = 0; i < KNN; ++i) m[i] = p0[i];
  for (int s = 1; s < jsplit; ++s) {
    const float* p = knn + ((size_t)s * NROWS + row) * KNN;
    float b[KNN];
    #pragma unroll
    for (int i = 0; i < KNN; ++i) b[i] = p[i];
    #pragma unroll
    for (int k = 0; k < KNN; ++k) m[k] = fminf(m[k], b[KNN - 1 - k]);
    clean8min(m);
  }
  float rs = 0.f;
  #pragma unroll
  for (int i = 0; i < KNN; ++i) rs += m[i];
  float s2 = sqn[row];

  __shared__ float red[2][4];
  #pragma unroll
  for (int off = 32; off > 0; off >>= 1) {
    rs += __shfl_down(rs, off);
    s2 += __shfl_down(s2, off);
  }
  if ((tid & 63) == 0) { red[0][tid >> 6] = rs; red[1][tid >> 6] = s2; }
  __syncthreads();
  if (tid == 0) {
    atomicAdd(&gacc[0], red[0][0] + red[0][1] + red[0][2] + red[0][3]);
    atomicAdd(&gacc[1], red[1][0] + red[1][1] + red[1][2] + red[1][3]);
  }
  if (blockIdx.x == 0) {
    float s = 0.f;
    for (int b = 0; b < 128; ++b) s += pcs[b * NDIM + tid];
    float q = s * s;
    #pragma unroll
    for (int off = 32; off > 0; off >>= 1) q += __shfl_down(q, off);
    __syncthreads();
    if ((tid & 63) == 0) red[0][tid >> 6] = q;
    __syncthreads();
    if (tid == 0) atomicAdd(&gacc[2], red[0][0] + red[0][1] + red[0][2] + red[0][3]);
  }
  // completion: last block computes the output scalar.
  if (tid == 0) {
    __threadfence();
    int* cnt = (int*)(gacc + 3);
    const int prev = atomicAdd(cnt, 1);
    if (prev == (int)gridDim.x - 1) {
      const float sum8 = atomicAdd(&gacc[0], 0.0f);
      const float S2   = atomicAdd(&gacc[1], 0.0f);
      const float Q    = atomicAdd(&gacc[2], 0.0f);
      const float ref_var = (S2 - Q / (float)NROWS) / ((float)NDIM * (float)(NROWS - 1));
      out[0] = (sum8 / (float)(NROWS * KNN)) / ref_var;
    }
  }
}

extern "C" void kernel_launch(void* const* d_in, const int* in_sizes, int n_in,
                              void* d_out, int out_size, void* d_ws, size_t ws_size,
                              hipStream_t stream) {
  const float* e = (const float*)d_in[0];
  char* ws = (char*)d_ws;
  ushort* ebf = (ushort*)(ws + WS_EBF);
  float* sqn  = (float*)(ws + WS_SQN);
  float* pcs  = (float*)(ws + WS_PCS);
  float* gacc = (float*)(ws + WS_ACC);
  float* knn  = (float*)(ws + WS_KNN);
  float* out  = (float*)d_out;

  const size_t need32 = (size_t)WS_KNN + (size_t)NROWS * 32 * KNN * 4;
  const int jsplit = (ws_size >= need32) ? 32 : 16;
  const int jrange = NROWS / jsplit;

  hipLaunchKernelGGL(k_prep,  dim3(128), dim3(256), 0, stream, e, ebf, sqn, pcs, gacc);
  hipLaunchKernelGGL(k_main,  dim3(NROWS / BLK_ROWS, jsplit), dim3(256), 0, stream,
                     ebf, sqn, knn, jrange, jsplit);
  hipLaunchKernelGGL(k_final, dim3(NROWS / 256), dim3(256), 0, stream,
                     knn, sqn, pcs, gacc, out, jsplit);
}

// Round 10
// 76.093 us; speedup vs baseline: 1.3224x; 1.3224x over previous
//
#include <hip/hip_runtime.h>
#include <hip/hip_bf16.h>

#define NROWS 8192
#define NDIM  256
#define KNN   8
#define TCOL  32                          // j-cols per LDS tile (16 KiB)
#define BLK_ROWS 128                      // 4 waves x 32 rows (R=1)

typedef __attribute__((ext_vector_type(8)))  short bf16x8;
typedef __attribute__((ext_vector_type(16))) float f32x16;

// ---- workspace layout (bytes) ----
// ebT chunk-major: ushort ebT[32][NROWS][8] — chunk c holds dims 8c..8c+7 of
// every row. Any 32-consecutive-row fragment load = contiguous 512 B.
#define WS_EBT 0                          // 4 MiB
#define WS_SQN (4*1024*1024)              // 32 KiB
#define WS_PCS (WS_SQN + 32*1024)         // 128 x 256 f32 = 128 KiB
#define WS_ACC (WS_PCS + 128*1024)        // gacc[0..2] + counter
#define WS_KNN (WS_ACC + 1024)            // [16][NROWS][KNN] f32 = 4 MiB

// e -> bf16 chunk-major, per-row squared norms, per-block colsum partials.
// Block 0 zeroes gacc+counter (only k_final reads them; stream-ordered).
__global__ void k_prep(const float* __restrict__ e,
                       ushort* __restrict__ ebt,
                       float* __restrict__ sqn,
                       float* __restrict__ pcs,
                       float* __restrict__ gacc) {
  __shared__ float lcs[NDIM];
  const int tid  = threadIdx.x;
  const int lane = tid & 63;
  const int wv   = tid >> 6;
  if (blockIdx.x == 0 && tid < 8) ((int*)gacc)[tid] = 0;
  lcs[tid] = 0.f;
  __syncthreads();
  const int chunk = lane >> 1;            // this lane's 4 dims live here
  const int half  = lane & 1;
  float4 cs = {0.f, 0.f, 0.f, 0.f};
  #pragma unroll
  for (int r = 0; r < 16; ++r) {
    const int row = blockIdx.x * 64 + wv * 16 + r;
    const float4 v = *reinterpret_cast<const float4*>(e + (size_t)row * NDIM + lane * 4);
    ushort4 o;
    __hip_bfloat16 b0 = __float2bfloat16(v.x), b1 = __float2bfloat16(v.y);
    __hip_bfloat16 b2 = __float2bfloat16(v.z), b3 = __float2bfloat16(v.w);
    o.x = *reinterpret_cast<ushort*>(&b0); o.y = *reinterpret_cast<ushort*>(&b1);
    o.z = *reinterpret_cast<ushort*>(&b2); o.w = *reinterpret_cast<ushort*>(&b3);
    *reinterpret_cast<ushort4*>(ebt + ((size_t)(chunk * NROWS + row) * 8 + half * 4)) = o;
    float acc = v.x*v.x + v.y*v.y + v.z*v.z + v.w*v.w;
    #pragma unroll
    for (int off = 32; off > 0; off >>= 1) acc += __shfl_down(acc, off);
    if (lane == 0) sqn[row] = acc;
    cs.x += v.x; cs.y += v.y; cs.z += v.z; cs.w += v.w;
  }
  atomicAdd(&lcs[lane * 4 + 0], cs.x);
  atomicAdd(&lcs[lane * 4 + 1], cs.y);
  atomicAdd(&lcs[lane * 4 + 2], cs.z);
  atomicAdd(&lcs[lane * 4 + 3], cs.w);
  __syncthreads();
  pcs[blockIdx.x * NDIM + tid] = lcs[tid];
}

// ---- selection helpers (MAX-key; key = dot - nj/2, larger = nearer) ----
__device__ __forceinline__ void CEmax(float& x, float& y) {
  const float hi = fmaxf(x, y);
  y = fminf(x, y);
  x = hi;
}
__device__ __forceinline__ void clean8max(float* s) {   // bitonic -> descending
  CEmax(s[0],s[4]); CEmax(s[1],s[5]); CEmax(s[2],s[6]); CEmax(s[3],s[7]);
  CEmax(s[0],s[2]); CEmax(s[1],s[3]); CEmax(s[4],s[6]); CEmax(s[5],s[7]);
  CEmax(s[0],s[1]); CEmax(s[2],s[3]); CEmax(s[4],s[5]); CEmax(s[6],s[7]);
}
__device__ __forceinline__ void ins8max(float* m, const float c) {  // desc insert
  m[7] = __builtin_amdgcn_fmed3f(m[6], m[7], c);
  m[6] = __builtin_amdgcn_fmed3f(m[5], m[6], c);
  m[5] = __builtin_amdgcn_fmed3f(m[4], m[5], c);
  m[4] = __builtin_amdgcn_fmed3f(m[3], m[4], c);
  m[3] = __builtin_amdgcn_fmed3f(m[2], m[3], c);
  m[2] = __builtin_amdgcn_fmed3f(m[1], m[2], c);
  m[1] = __builtin_amdgcn_fmed3f(m[0], m[1], c);
  m[0] = fmaxf(m[0], c);
}
__device__ __forceinline__ void CEmin(float& x, float& y) {
  const float lo = fminf(x, y);
  y = fmaxf(x, y);
  x = lo;
}
__device__ __forceinline__ void clean8min(float* s) {   // bitonic -> ascending
  CEmin(s[0],s[4]); CEmin(s[1],s[5]); CEmin(s[2],s[6]); CEmin(s[3],s[7]);
  CEmin(s[0],s[2]); CEmin(s[1],s[3]); CEmin(s[4],s[6]); CEmin(s[5],s[7]);
  CEmin(s[0],s[1]); CEmin(s[2],s[3]); CEmin(s[4],s[5]); CEmin(s[6],s[7]);
}

// Fused Gram + top-8. R=1 (32 rows/wave) for ~115 live VGPR -> 4 blocks/CU:
// each SIMD hosts 4 waves from 4 DIFFERENT blocks (independent barriers) so
// one block's selection VALU overlaps another's MFMA (phase diversity —
// the r6-r9 structures all serialized these bursts at 2 blocks/CU).
// ebT chunk-major: ifrag prologue loads coalesced (512 B segments), stage
// sources contiguous, LDS reads contiguous 1 KiB/wave -> 0 conflicts, no
// swizzle anywhere. acc init = -nj/2 so the MFMA output IS the selection key.
__launch_bounds__(256, 4)
__global__ void k_main(const ushort* __restrict__ ebt,
                       const float* __restrict__ sqn,
                       float* __restrict__ knn_out,
                       int jrange, int jsplit) {
  __shared__ ushort lbuf[2][TCOL * NDIM];   // 2 x 16 KiB
  char* const lraw = reinterpret_cast<char*>(&lbuf[0][0]);

  const int tid  = threadIdx.x;
  const int lane = tid & 63;
  const int wv   = tid >> 6;
  const int col  = lane & 31;
  const int hi   = lane >> 5;
  const int rowi = blockIdx.x * BLK_ROWS + wv * 32 + col;
  const int split = blockIdx.y;
  const int jbase = split * jrange;

  // i-fragments: chunk 2kk+hi, row rowi -> coalesced 512 B per half-wave.
  bf16x8 ifr[16];
  #pragma unroll
  for (int kk = 0; kk < 16; ++kk)
    ifr[kk] = *reinterpret_cast<const bf16x8*>(
        ebt + (size_t)((2 * kk + hi) * NROWS + rowi) * 8);
  const float ni = sqn[rowi];

  float m[KNN];
  #pragma unroll
  for (int i = 0; i < KNN; ++i) m[i] = -1e30f;

  // hoisted stage source pointers: thread tid covers chunk c = s*8+(tid>>5),
  // col = tid&31; contiguous 512 B per 32 lanes. Advance 32 rows per tile.
  const ushort* sp[4];
  #pragma unroll
  for (int s = 0; s < 4; ++s) {
    const int c = s * 8 + (tid >> 5);
    sp[s] = ebt + (size_t)(c * NROWS + jbase + (tid & 31)) * 8;
  }
  const int lbase = hi * 512 + col * 16;   // ds_read lane base (contiguous)

  auto STAGE = [&](int bufc) {
    #pragma unroll
    for (int s = 0; s < 4; ++s) {
      __builtin_amdgcn_global_load_lds(
          (const __attribute__((address_space(1))) void*)sp[s],
          (__attribute__((address_space(3))) void*)(
              lraw + bufc * 16384 + s * 4096 + wv * 1024),
          16, 0, 0);
      sp[s] += TCOL * 8;
    }
  };

  const float* njp = sqn + jbase;
  const int nT = jrange / TCOL;   // 16 (even)

  STAGE(0);
  asm volatile("s_waitcnt vmcnt(0)" ::: "memory");
  __syncthreads();

  auto BODY = [&](int bufc, int t) {
    if (t + 1 < nT) STAGE(bufc ^ 1);

    // acc init = -nj/2 for this reg's j: j_local = 8*(r>>2)+(r&3)+4*hi
    f32x16 acc;
    #pragma unroll
    for (int g = 0; g < 4; ++g) {
      const float4 nj4 = *reinterpret_cast<const float4*>(njp + g * 8 + hi * 4);
      acc[g*4+0] = -0.5f * nj4.x; acc[g*4+1] = -0.5f * nj4.y;
      acc[g*4+2] = -0.5f * nj4.z; acc[g*4+3] = -0.5f * nj4.w;
    }
    #pragma unroll
    for (int kk = 0; kk < 16; ++kk) {
      const bf16x8 jf = *reinterpret_cast<const bf16x8*>(
          lraw + bufc * 16384 + kk * 1024 + lbase);
      acc = __builtin_amdgcn_mfma_f32_32x32x16_bf16(jf, ifr[kk], acc, 0, 0, 0);
    }
    #pragma unroll
    for (int q = 0; q < 16; ++q) ins8max(m, acc[q]);

    njp += TCOL;
    asm volatile("s_waitcnt vmcnt(0)" ::: "memory");
    __syncthreads();
  };

  for (int t = 0; t < nT; t += 2) {
    BODY(0, t);
    BODY(1, t + 1);
  }

  // merge k-half lists (lane <-> lane+32): top-8 of two descending lists is
  // elementwise max(a_k, b_{7-k}) (bitonic) -> clean. dist = ni - 2*key.
  float g[KNN];
  #pragma unroll
  for (int k = 0; k < KNN; ++k)
    g[k] = fmaxf(m[k], __shfl_xor(m[KNN - 1 - k], 32));
  clean8max(g);
  if (hi == 0) {
    float* dst = knn_out + ((size_t)split * NROWS + rowi) * KNN;
    #pragma unroll
    for (int k = 0; k < KNN; ++k)
      dst[k] = fmaxf(fmaf(-2.0f, g[k], ni), 0.0f);   // ascending distances
  }
}

// Merge jsplit ascending sorted 8-lists per row; reduce sum8/S2; block 0
// reduces colsum partials -> Q; last finishing block computes the scalar.
__global__ void k_final(const float* __restrict__ knn,
                        const float* __restrict__ sqn,
                        const float* __restrict__ pcs,
                        float* __restrict__ gacc,
                        float* __restrict__ out, int jsplit) {
  const int tid = threadIdx.x;
  const int row = blockIdx.x * blockDim.x + tid;
  float m[KNN];
  const float* p0 = knn + (size_t)row * KNN;
  #pragma unroll
  for (int i = 0; i < KNN; ++i) m[i] = p0[i];
  for (int s = 1; s < jsplit; ++s) {
    const float* p = knn + ((size_t)s * NROWS + row) * KNN;
    float b[KNN];
    #pragma unroll
    for (int i = 0; i < KNN; ++i) b[i] = p[i];
    #pragma unroll
    for (int k = 0; k < KNN; ++k) m[k] = fminf(m[k], b[KNN - 1 - k]);
    clean8min(m);
  }
  float rs = 0.f;
  #pragma unroll
  for (int i = 0; i < KNN; ++i) rs += m[i];
  float s2 = sqn[row];

  __shared__ float red[2][4];
  #pragma unroll
  for (int off = 32; off > 0; off >>= 1) {
    rs += __shfl_down(rs, off);
    s2 += __shfl_down(s2, off);
  }
  if ((tid & 63) == 0) { red[0][tid >> 6] = rs; red[1][tid >> 6] = s2; }
  __syncthreads();
  if (tid == 0) {
    atomicAdd(&gacc[0], red[0][0] + red[0][1] + red[0][2] + red[0][3]);
    atomicAdd(&gacc[1], red[1][0] + red[1][1] + red[1][2] + red[1][3]);
  }
  if (blockIdx.x == 0) {
    float s = 0.f;
    for (int b = 0; b < 128; ++b) s += pcs[b * NDIM + tid];
    float q = s * s;
    #pragma unroll
    for (int off = 32; off > 0; off >>= 1) q += __shfl_down(q, off);
    __syncthreads();
    if ((tid & 63) == 0) red[0][tid >> 6] = q;
    __syncthreads();
    if (tid == 0) atomicAdd(&gacc[2], red[0][0] + red[0][1] + red[0][2] + red[0][3]);
  }
  // completion: last block computes the output scalar.
  if (tid == 0) {
    __threadfence();
    int* cnt = (int*)(gacc + 3);
    const int prev = atomicAdd(cnt, 1);
    if (prev == (int)gridDim.x - 1) {
      const float sum8 = atomicAdd(&gacc[0], 0.0f);
      const float S2   = atomicAdd(&gacc[1], 0.0f);
      const float Q    = atomicAdd(&gacc[2], 0.0f);
      const float ref_var = (S2 - Q / (float)NROWS) / ((float)NDIM * (float)(NROWS - 1));
      out[0] = (sum8 / (float)(NROWS * KNN)) / ref_var;
    }
  }
}

extern "C" void kernel_launch(void* const* d_in, const int* in_sizes, int n_in,
                              void* d_out, int out_size, void* d_ws, size_t ws_size,
                              hipStream_t stream) {
  const float* e = (const float*)d_in[0];
  char* ws = (char*)d_ws;
  ushort* ebt = (ushort*)(ws + WS_EBT);
  float* sqn  = (float*)(ws + WS_SQN);
  float* pcs  = (float*)(ws + WS_PCS);
  float* gacc = (float*)(ws + WS_ACC);
  float* knn  = (float*)(ws + WS_KNN);
  float* out  = (float*)d_out;

  const int jsplit = 16;
  const int jrange = NROWS / jsplit;   // 512 -> nT = 16

  hipLaunchKernelGGL(k_prep,  dim3(128), dim3(256), 0, stream, e, ebt, sqn, pcs, gacc);
  hipLaunchKernelGGL(k_main,  dim3(NROWS / BLK_ROWS, jsplit), dim3(256), 0, stream,
                     ebt, sqn, knn, jrange, jsplit);
  hipLaunchKernelGGL(k_final, dim3(NROWS / 256), dim3(256), 0, stream,
                     knn, sqn, pcs, gacc, out, jsplit);
}